// Round 6
// baseline (207.760 us; speedup 1.0000x reference)
//
#include <hip/hip_runtime.h>
#include <stdint.h>

#define BB 128
#define NN 32768
#define CI 6
#define TOPK 400
#define PADK 448           // TOPK padded to full 64-lane words (zero boxes)
#define KEEPK 200
#define SORTN 1024
#define NT 1024
#define KQT 8              // uint4 per thread: 8*4 = 32 keys = NN / NT
#define NBUCK 4096
#define KEY0 0x3F000000u   // float bits of 0.5f
#define STILE 1024         // rows per score block

// Exact-decision IoU constant: RN32(inter/denom) > 0.5f  <=>  inter > denom*(0.5+2^-25),
// and denom(24b) * C(26b) is exact in f64 -> bit-identical keep decisions without v_div.
#define IOU_C 0.50000002980232238769531250

// ---------------- K1: full-GPU score pass, LDS-staged coalescing ----------------
__global__ __launch_bounds__(256) void score_kernel(
        const float* __restrict__ pred, uint32_t* __restrict__ keys) {
    __shared__ float lf[STILE * 6];                    // 24 KB
    const int t = threadIdx.x;
    const float4* p4 = reinterpret_cast<const float4*>(pred) +
                       (size_t)blockIdx.x * (STILE * 6 / 4);
    float4* l4 = reinterpret_cast<float4*>(lf);
#pragma unroll
    for (int k = 0; k < 6; k++) l4[t + 256 * k] = p4[t + 256 * k];
    __syncthreads();
    uint4 o;
    { float s = fmaxf(lf[24 * t +  4], lf[24 * t +  5]); o.x = (s > 0.5f) ? __float_as_uint(s) : 0u; }
    { float s = fmaxf(lf[24 * t + 10], lf[24 * t + 11]); o.y = (s > 0.5f) ? __float_as_uint(s) : 0u; }
    { float s = fmaxf(lf[24 * t + 16], lf[24 * t + 17]); o.z = (s > 0.5f) ? __float_as_uint(s) : 0u; }
    { float s = fmaxf(lf[24 * t + 22], lf[24 * t + 23]); o.w = (s > 0.5f) ? __float_as_uint(s) : 0u; }
    reinterpret_cast<uint4*>(keys)[blockIdx.x * 256 + t] = o;
}

// ---------------- K2: per-image select + order + decode + NMS ----------------
__global__ __launch_bounds__(NT) void boxsel2_kernel(
        const float* __restrict__ pred, const float* __restrict__ priors,
        const uint32_t* __restrict__ keys, float* __restrict__ out) {
    const int b = blockIdx.x;
    const int tid = threadIdx.x;
    const int lane = tid & 63;
    const int wid = tid >> 6;                 // 0..15
    const float* img = pred + (size_t)b * (NN * CI);
    float* oimg = out + (size_t)b * KEEPK * 6;

    __shared__ union {
        unsigned int hist[4][NBUCK];          // 64 KB, phase 2 only
        struct {                              // phases 3-8 (hist dead)
            unsigned long long cbuf[SORTN];               // gather-order composites
            float4 cbox[PADK];                            // rank-order, zero pad
            float car[PADK], csc[TOPK];
            int clab[TOPK];
            unsigned long long supm[TOPK * 7 + 8];        // stride 7 + pad
        } s;
    } u;
    __shared__ unsigned int wavetot[16];
    __shared__ unsigned int sh_bucket, ccount;
    __shared__ unsigned long long keepw[8];

    // zero output rows (d_out poisoned before every launch)
    for (int i = tid; i < KEEPK * 6; i += NT) oimg[i] = 0.0f;

    // ---- phase 1: coalesced uint4 key load (128 KB per image)
    uint4 kq[KQT];
    const uint4* k4 = reinterpret_cast<const uint4*>(keys + (size_t)b * NN);
#pragma unroll
    for (int uu = 0; uu < KQT; uu++) kq[uu] = k4[tid + (uu << 10)];

    if (tid == 0) { sh_bucket = 0; ccount = 0; }
    {   // zero 64 KB hist via uint4 stores (4 per thread)
        uint4* hz = reinterpret_cast<uint4*>(u.hist);
#pragma unroll
        for (int k = 0; k < 4; k++) hz[tid + k * NT] = make_uint4(0u, 0u, 0u, 0u);
    }
    __syncthreads();

    // ---- phase 2a: single-pass histogram, 4 copies (cuts same-bucket chains)
    const int hc = wid & 3;
#pragma unroll
    for (int uu = 0; uu < KQT; uu++) {
        uint32_t k0 = kq[uu].x, k1 = kq[uu].y, k2 = kq[uu].z, k3 = kq[uu].w;
        if (k0) { unsigned int bu = (k0 - KEY0) >> 13; if (bu > NBUCK - 1u) bu = NBUCK - 1u; atomicAdd(&u.hist[hc][bu], 1u); }
        if (k1) { unsigned int bu = (k1 - KEY0) >> 13; if (bu > NBUCK - 1u) bu = NBUCK - 1u; atomicAdd(&u.hist[hc][bu], 1u); }
        if (k2) { unsigned int bu = (k2 - KEY0) >> 13; if (bu > NBUCK - 1u) bu = NBUCK - 1u; atomicAdd(&u.hist[hc][bu], 1u); }
        if (k3) { unsigned int bu = (k3 - KEY0) >> 13; if (bu > NBUCK - 1u) bu = NBUCK - 1u; atomicAdd(&u.hist[hc][bu], 1u); }
    }
    __syncthreads();

    // ---- phase 2b: merge copies + suffix scan; thread owns buckets 4t..4t+3
    unsigned int h0 = u.hist[0][4 * tid + 0] + u.hist[1][4 * tid + 0] + u.hist[2][4 * tid + 0] + u.hist[3][4 * tid + 0];
    unsigned int h1 = u.hist[0][4 * tid + 1] + u.hist[1][4 * tid + 1] + u.hist[2][4 * tid + 1] + u.hist[3][4 * tid + 1];
    unsigned int h2 = u.hist[0][4 * tid + 2] + u.hist[1][4 * tid + 2] + u.hist[2][4 * tid + 2] + u.hist[3][4 * tid + 2];
    unsigned int h3 = u.hist[0][4 * tid + 3] + u.hist[1][4 * tid + 3] + u.hist[2][4 * tid + 3] + u.hist[3][4 * tid + 3];
    unsigned int sum = h0 + h1 + h2 + h3;
    unsigned int suf = sum;                   // wave inclusive suffix sum
#pragma unroll
    for (int off = 1; off < 64; off <<= 1) {
        unsigned int v = __shfl_down(suf, off);
        if (lane + off < 64) suf += v;
    }
    if (lane == 0) wavetot[wid] = suf;
    __syncthreads();
    if (tid < 16) {                           // exclusive suffix over waves
        unsigned int wv = wavetot[tid];
        unsigned int ws = wv;
#pragma unroll
        for (int off = 1; off < 16; off <<= 1) {
            unsigned int v = __shfl_down(ws, off);
            if (tid + off < 16) ws += v;
        }
        wavetot[tid] = ws - wv;
    }
    __syncthreads();
    unsigned int acc = wavetot[wid] + (suf - sum);   // count strictly above my 4
    if (acc < TOPK && acc + h3 >= TOPK) sh_bucket = 4 * tid + 3;
    acc += h3;
    if (acc < TOPK && acc + h2 >= TOPK) sh_bucket = 4 * tid + 2;
    acc += h2;
    if (acc < TOPK && acc + h1 >= TOPK) sh_bucket = 4 * tid + 1;
    acc += h1;
    if (acc < TOPK && acc + h0 >= TOPK) sh_bucket = 4 * tid + 0;
    __syncthreads();
    // bucket(key) >= B  <=>  key >= KEY0 + (B<<13); all stored keys > KEY0.
    const uint32_t Tkey = KEY0 + (sh_bucket << 13);

    // ---- phase 3: gather composites (key, ~idx), WAVE-AGGREGATED counter:
    // one atomicAdd per wave per site (ballot + prefix-popcount scatter).
    // Gather order is irrelevant (phase 4 ranks by value).
#pragma unroll
    for (int uu = 0; uu < KQT; uu++) {
        uint32_t kk[4] = { kq[uu].x, kq[uu].y, kq[uu].z, kq[uu].w };
#pragma unroll
        for (int j = 0; j < 4; j++) {
            uint32_t key = kk[j];
            bool pr = (key >= Tkey);
            unsigned long long m = __ballot(pr);
            if (m != 0ull) {
                int leader = (int)(__ffsll((long long)m) - 1);
                unsigned int base = 0;
                if (lane == leader) base = atomicAdd(&ccount, (unsigned int)__popcll(m));
                base = (unsigned int)__shfl((int)base, leader);
                if (pr) {
                    unsigned int pfx = (unsigned int)__popcll(m & ((1ull << lane) - 1ull));
                    unsigned int p = base + pfx;
                    if (p < SORTN) {
                        unsigned int idx = ((unsigned int)(tid + (uu << 10)) << 2) + (unsigned int)j;
                        u.s.cbuf[p] = ((unsigned long long)key << 32) |
                                      (unsigned long long)(0xFFFFFFFFu - idx);
                    }
                }
            }
        }
    }
    __syncthreads();

    // ---- phase 4: fused decode + rank-by-count + permute.
    // Composites preloaded into per-wave registers (identical copies); the
    // compare loop broadcasts via v_readlane (uniform index) -> runs on the
    // 4 VALU pipes instead of the single shared LDS pipe. Compile-time
    // chunk indexing only (no dynamic register indexing). cnt>448 tail is
    // handled exactly via LDS. Decode loads issue first; rank loop covers
    // their latency; results land directly at rank position.
    const unsigned int cnt = (ccount < SORTN) ? ccount : SORTN;
    for (int i2 = tid; i2 < TOPK * 7 + 8; i2 += NT) u.s.supm[i2] = 0ull;
    if (tid >= TOPK && tid < PADK) {          // zero pad: never suppresses
        u.s.cbox[tid] = make_float4(0.f, 0.f, 0.f, 0.f);
        u.s.car[tid] = 0.f;
    }
    if (tid < 8) {
        int cntc = (cnt < TOPK) ? (int)cnt : TOPK;
        int rem = cntc - (tid << 6);
        keepw[tid] = (rem <= 0) ? 0ull : ((rem >= 64) ? ~0ull : ((1ull << rem) - 1ull));
    }
    unsigned long long rv0 = 0, rv1 = 0, rv2 = 0, rv3 = 0, rv4 = 0, rv5 = 0, rv6 = 0;
    if ((unsigned int)(wid << 6) < cnt) {     // wave contains a candidate
        rv0 = u.s.cbuf[lane];
        rv1 = u.s.cbuf[64 + lane];
        rv2 = u.s.cbuf[128 + lane];
        rv3 = u.s.cbuf[192 + lane];
        rv4 = u.s.cbuf[256 + lane];
        rv5 = u.s.cbuf[320 + lane];
        rv6 = u.s.cbuf[384 + lane];
    }
    if ((unsigned int)tid < cnt) {
        unsigned long long ct = u.s.cbuf[tid];
        uint32_t key = (uint32_t)(ct >> 32);
        uint32_t idx = 0xFFFFFFFFu - (uint32_t)(ct & 0xFFFFFFFFull);
        const float* p = img + (size_t)idx * CI;          // issue scattered loads early
        float l0 = p[0], l1 = p[1], l2 = p[2], l3 = p[3], c0 = p[4], c1 = p[5];
        const float* pr = priors + (size_t)idx * 4;
        float px = pr[0], py = pr[1], pw = pr[2], ph = pr[3];
        unsigned int rank = 0;                            // covers load latency
#define RCHUNK(K, RV)                                                         \
        { unsigned int basej = (unsigned int)(K) << 6;                        \
          if (basej < cnt) {                                                  \
            unsigned int lim = cnt - basej; if (lim > 64u) lim = 64u;         \
            for (unsigned int j2 = 0; j2 < lim; j2++) {                       \
                unsigned int blo = (unsigned int)__builtin_amdgcn_readlane(   \
                    (int)(unsigned int)(RV), (int)j2);                        \
                unsigned int bhi = (unsigned int)__builtin_amdgcn_readlane(   \
                    (int)(unsigned int)((RV) >> 32), (int)j2);                \
                unsigned long long bj =                                       \
                    ((unsigned long long)bhi << 32) | (unsigned long long)blo;\
                rank += (bj > ct) ? 1u : 0u;                                  \
            } } }
        RCHUNK(0, rv0) RCHUNK(1, rv1) RCHUNK(2, rv2) RCHUNK(3, rv3)
        RCHUNK(4, rv4) RCHUNK(5, rv5) RCHUNK(6, rv6)
#undef RCHUNK
        for (unsigned int jj = 448; jj < cnt; jj++)       // exact tail (rare)
            rank += (u.s.cbuf[jj] > ct) ? 1u : 0u;
        // reference float op order; no fma
        float cxv = __fadd_rn(px, __fmul_rn(__fmul_rn(l0, 0.1f), pw));
        float cyv = __fadd_rn(py, __fmul_rn(__fmul_rn(l1, 0.1f), ph));
        float ew = __fmul_rn(pw, expf(__fmul_rn(l2, 0.2f)));
        float eh = __fmul_rn(ph, expf(__fmul_rn(l3, 0.2f)));
        float hw = __fmul_rn(ew, 0.5f);
        float hh = __fmul_rn(eh, 0.5f);
        float x1 = __fsub_rn(cxv, hw), y1 = __fsub_rn(cyv, hh);
        float x2 = __fadd_rn(cxv, hw), y2 = __fadd_rn(cyv, hh);
        if (rank < TOPK) {
            u.s.cbox[rank] = make_float4(x1, y1, x2, y2);
            u.s.car[rank] = __fmul_rn(__fsub_rn(x2, x1), __fsub_rn(y2, y1));
            u.s.csc[rank] = __uint_as_float(key);
            u.s.clab[rank] = (c1 > c0) ? 1 : 0;
        }
    }
    __syncthreads();

    // ---- phase 6: suppression bit-matrix via per-wave ballot.
    {
        float4 bjv[7]; float ajv[7];
#pragma unroll
        for (int jw = 0; jw < 7; jw++) {
            int j = (jw << 6) + lane;
            bjv[jw] = u.s.cbox[j];
            ajv[jw] = u.s.car[j];
        }
        float4 bi = u.s.cbox[wid];
        float ai = u.s.car[wid];
        for (int i = wid; i < TOPK; i += 16) {
            float4 bi_n = u.s.cbox[i + 16];   // prefetch next row (pad-safe)
            float ai_n = u.s.car[i + 16];
            const int jw0 = i >> 6;           // wave-uniform
            unsigned long long dmask = (~0ull << (i & 63)) << 1;
#pragma unroll
            for (int jw = 0; jw < 7; jw++) {
                if (jw < jw0) continue;
                float4 bj = bjv[jw]; float aj = ajv[jw];
                float iw = fmaxf(__fsub_rn(fminf(bi.z, bj.z), fmaxf(bi.x, bj.x)), 0.0f);
                float ih = fmaxf(__fsub_rn(fminf(bi.w, bj.w), fmaxf(bi.y, bj.y)), 0.0f);
                float inter = __fmul_rn(iw, ih);
                float denom = __fadd_rn(__fsub_rn(__fadd_rn(ai, aj), inter), 1e-12f);
                bool bit = (double)inter > (double)denom * IOU_C;
                unsigned long long word = __ballot(bit);
                if (lane == 0) {
                    if (jw == jw0) word &= dmask;
                    u.s.supm[i * 7 + jw] = word;
                }
            }
            bi = bi_n; ai = ai_n;
        }
    }
    __syncthreads();

    // ---- phase 7: sequential resolve; readlane (VALU->SGPR) chain
    if (tid < 64) {
        int w = tid & 7;                     // lanes 0-6 own words; rest shadow
        unsigned long long kw = keepw[w];
        unsigned long long rr[16], nn[16];   // compile-time-indexed after unroll
#pragma unroll
        for (int k = 0; k < 16; k++) rr[k] = u.s.supm[k * 7 + w];
        for (int base = 0; base < TOPK; base += 16) {
            int nb = base + 16;
            int gb = (nb < TOPK) ? nb : base;
#pragma unroll
            for (int k = 0; k < 16; k++) nn[k] = u.s.supm[(gb + k) * 7 + w];
#pragma unroll
            for (int k = 0; k < 16; k++) {
                int i = base + k;
                unsigned int lo = (unsigned int)__builtin_amdgcn_readlane((int)(unsigned int)kw, i >> 6);
                unsigned int hi = (unsigned int)__builtin_amdgcn_readlane((int)(unsigned int)(kw >> 32), i >> 6);
                unsigned int sel = ((i & 63) < 32) ? lo : hi;
                if ((sel >> (i & 31)) & 1u) kw &= ~rr[k];
            }
#pragma unroll
            for (int k = 0; k < 16; k++) rr[k] = nn[k];
        }
        if (tid < 7) keepw[tid] = kw;
    }
    __syncthreads();

    // ---- phase 8: rank via suffix-popcount over kept (csc is sorted desc),
    // exact tie correction by local walk (ties are O(0) for float scores).
    if (tid < TOPK) {
        const int t = tid;
        if ((keepw[t >> 6] >> (t & 63)) & 1ull) {
            float st = u.s.csc[t];
            int rank = 0;
#pragma unroll
            for (int w = 0; w < 7; w++) {
                unsigned long long kws = keepw[w];
                int jb = w << 6;
                unsigned long long m;
                if (t >= jb + 63)      m = 0ull;           // no bits > t here
                else if (t < jb)       m = ~0ull;          // whole word > t
                else                   m = ~((1ull << (t - jb + 1)) - 1ull);
                rank += __popcll(kws & m);
            }
            for (int j = t + 1; j < TOPK && u.s.csc[j] == st; j++)
                if ((keepw[j >> 6] >> (j & 63)) & 1ull) rank--;
            for (int j = t - 1; j >= 0 && u.s.csc[j] == st; j--)
                if ((keepw[j >> 6] >> (j & 63)) & 1ull) rank++;
            if (rank < KEEPK) {
                float4 bx = u.s.cbox[t];
                float* row = oimg + (size_t)rank * 6;
                row[0] = (float)u.s.clab[t];
                row[1] = st;
                row[2] = bx.x; row[3] = bx.y; row[4] = bx.z; row[5] = bx.w;
            }
        }
    }
}

extern "C" void kernel_launch(void* const* d_in, const int* in_sizes, int n_in,
                              void* d_out, int out_size, void* d_ws, size_t ws_size,
                              hipStream_t stream) {
    const float* pred = (const float*)d_in[0];     // (128, 32768, 6)
    const float* priors = (const float*)d_in[1];   // (32768, 4)
    float* out = (float*)d_out;                    // (128, 200, 6)
    uint32_t* keys = (uint32_t*)d_ws;              // 16 MB scratch
    score_kernel<<<(BB * NN) / STILE, 256, 0, stream>>>(pred, keys);
    boxsel2_kernel<<<BB, NT, 0, stream>>>(pred, priors, keys, out);
}

// Round 7
// 194.078 us; speedup vs baseline: 1.0705x; 1.0705x over previous
//
#include <hip/hip_runtime.h>
#include <stdint.h>

#define BB 128
#define NN 32768
#define CI 6
#define TOPK 400
#define PADK 448           // TOPK padded to full 64-lane words (zero boxes)
#define KEEPK 200
#define SORTN 1024
#define NT 1024
#define KQT 8              // uint4 per thread: 8*4 = 32 keys = NN / NT
#define NBUCK 4096
#define KEY0 0x3F000000u   // float bits of 0.5f
#define STILE 1024         // rows per score block

// Exact-decision IoU constant: RN32(inter/denom) > 0.5f  <=>  inter > denom*(0.5+2^-25),
// and denom(24b) * C(26b) is exact in f64 -> bit-identical keep decisions without v_div.
#define IOU_C 0.50000002980232238769531250

// ---------------- K1: full-GPU score pass, LDS-staged coalescing ----------------
__global__ __launch_bounds__(256) void score_kernel(
        const float* __restrict__ pred, uint32_t* __restrict__ keys) {
    __shared__ float lf[STILE * 6];                    // 24 KB
    const int t = threadIdx.x;
    const float4* p4 = reinterpret_cast<const float4*>(pred) +
                       (size_t)blockIdx.x * (STILE * 6 / 4);
    float4* l4 = reinterpret_cast<float4*>(lf);
#pragma unroll
    for (int k = 0; k < 6; k++) l4[t + 256 * k] = p4[t + 256 * k];
    __syncthreads();
    uint4 o;
    { float s = fmaxf(lf[24 * t +  4], lf[24 * t +  5]); o.x = (s > 0.5f) ? __float_as_uint(s) : 0u; }
    { float s = fmaxf(lf[24 * t + 10], lf[24 * t + 11]); o.y = (s > 0.5f) ? __float_as_uint(s) : 0u; }
    { float s = fmaxf(lf[24 * t + 16], lf[24 * t + 17]); o.z = (s > 0.5f) ? __float_as_uint(s) : 0u; }
    { float s = fmaxf(lf[24 * t + 22], lf[24 * t + 23]); o.w = (s > 0.5f) ? __float_as_uint(s) : 0u; }
    reinterpret_cast<uint4*>(keys)[blockIdx.x * 256 + t] = o;
}

// ---------------- K2: per-image select + order + decode + NMS ----------------
__global__ __launch_bounds__(NT) void boxsel2_kernel(
        const float* __restrict__ pred, const float* __restrict__ priors,
        const uint32_t* __restrict__ keys, float* __restrict__ out) {
    const int b = blockIdx.x;
    const int tid = threadIdx.x;
    const int lane = tid & 63;
    const int wid = tid >> 6;                 // 0..15
    const float* img = pred + (size_t)b * (NN * CI);
    float* oimg = out + (size_t)b * KEEPK * 6;

    __shared__ union {
        unsigned int hist[4][NBUCK];          // 64 KB, phases 1-2 only
        struct {                              // phases 3-8 (hist dead)
            unsigned long long cbuf[SORTN];               // rank-ordered composites
            float4 cbox[PADK];                            // rank-order, zero pad
            float car[PADK], csc[TOPK];
            int clab[TOPK];
            unsigned long long supm[TOPK * 7 + 8];        // stride 7 + pad
        } s;
    } u;
    __shared__ __align__(16) unsigned int hsuf[NBUCK];  // keys in buckets > bu
    __shared__ __align__(16) unsigned int bcnt[NBUCK];  // per-bucket placement ctr
    __shared__ unsigned int wavetot[16];
    __shared__ unsigned int sh_bucket, sh_cnt;
    __shared__ unsigned long long keepw[8];

    // zero output rows (d_out poisoned before every launch)
    for (int i = tid; i < KEEPK * 6; i += NT) oimg[i] = 0.0f;

    // ---- phase 1: coalesced uint4 key load (128 KB per image)
    uint4 kq[KQT];
    const uint4* k4 = reinterpret_cast<const uint4*>(keys + (size_t)b * NN);
#pragma unroll
    for (int uu = 0; uu < KQT; uu++) kq[uu] = k4[tid + (uu << 10)];

    if (tid == 0) { sh_bucket = 0; sh_cnt = 0; }
    {   // zero 64 KB hist (4 uint4/thread) + 16 KB bcnt (1 uint4/thread)
        uint4* hz = reinterpret_cast<uint4*>(u.hist);
#pragma unroll
        for (int k = 0; k < 4; k++) hz[tid + k * NT] = make_uint4(0u, 0u, 0u, 0u);
        reinterpret_cast<uint4*>(bcnt)[tid] = make_uint4(0u, 0u, 0u, 0u);
    }
    __syncthreads();

    // ---- phase 2a: single-pass histogram, 4 copies (cuts same-bucket chains)
    const int hc = wid & 3;
#pragma unroll
    for (int uu = 0; uu < KQT; uu++) {
        uint32_t k0 = kq[uu].x, k1 = kq[uu].y, k2 = kq[uu].z, k3 = kq[uu].w;
        if (k0) { unsigned int bu = (k0 - KEY0) >> 13; if (bu > NBUCK - 1u) bu = NBUCK - 1u; atomicAdd(&u.hist[hc][bu], 1u); }
        if (k1) { unsigned int bu = (k1 - KEY0) >> 13; if (bu > NBUCK - 1u) bu = NBUCK - 1u; atomicAdd(&u.hist[hc][bu], 1u); }
        if (k2) { unsigned int bu = (k2 - KEY0) >> 13; if (bu > NBUCK - 1u) bu = NBUCK - 1u; atomicAdd(&u.hist[hc][bu], 1u); }
        if (k3) { unsigned int bu = (k3 - KEY0) >> 13; if (bu > NBUCK - 1u) bu = NBUCK - 1u; atomicAdd(&u.hist[hc][bu], 1u); }
    }
    __syncthreads();

    // ---- phase 2b: merge copies + suffix scan; thread owns buckets 4t..4t+3.
    // Also writes hsuf[] (suffix counts) and sh_cnt (exact candidate count).
    unsigned int h0 = u.hist[0][4 * tid + 0] + u.hist[1][4 * tid + 0] + u.hist[2][4 * tid + 0] + u.hist[3][4 * tid + 0];
    unsigned int h1 = u.hist[0][4 * tid + 1] + u.hist[1][4 * tid + 1] + u.hist[2][4 * tid + 1] + u.hist[3][4 * tid + 1];
    unsigned int h2 = u.hist[0][4 * tid + 2] + u.hist[1][4 * tid + 2] + u.hist[2][4 * tid + 2] + u.hist[3][4 * tid + 2];
    unsigned int h3 = u.hist[0][4 * tid + 3] + u.hist[1][4 * tid + 3] + u.hist[2][4 * tid + 3] + u.hist[3][4 * tid + 3];
    unsigned int sum = h0 + h1 + h2 + h3;
    unsigned int suf = sum;                   // wave inclusive suffix sum
#pragma unroll
    for (int off = 1; off < 64; off <<= 1) {
        unsigned int v = __shfl_down(suf, off);
        if (lane + off < 64) suf += v;
    }
    if (lane == 0) wavetot[wid] = suf;
    __syncthreads();
    // hist fully read -> zero cbuf (overlays hist[0][0..2047]); gather relies
    // on unwritten slots reading as 0 (key==0 => invalid in decode).
    u.s.cbuf[tid] = 0ull;
    if (tid < 16) {                           // exclusive suffix over waves
        unsigned int wv = wavetot[tid];
        unsigned int ws = wv;
#pragma unroll
        for (int off = 1; off < 16; off <<= 1) {
            unsigned int v = __shfl_down(ws, off);
            if (tid + off < 16) ws += v;
        }
        wavetot[tid] = ws - wv;
    }
    __syncthreads();
    {
        unsigned int a3 = wavetot[wid] + (suf - sum);   // above bucket 4t+3
        unsigned int a2 = a3 + h3;
        unsigned int a1 = a2 + h2;
        unsigned int a0 = a1 + h1;
        unsigned int tot = a0 + h0;
        *reinterpret_cast<uint4*>(&hsuf[4 * tid]) = make_uint4(a0, a1, a2, a3);
        if (a3 < TOPK && a2 >= TOPK)  { sh_bucket = 4 * tid + 3; sh_cnt = a2; }
        if (a2 < TOPK && a1 >= TOPK)  { sh_bucket = 4 * tid + 2; sh_cnt = a1; }
        if (a1 < TOPK && a0 >= TOPK)  { sh_bucket = 4 * tid + 1; sh_cnt = a0; }
        if (a0 < TOPK && tot >= TOPK) { sh_bucket = 4 * tid + 0; sh_cnt = tot; }
        if (tid == 0 && tot < TOPK) sh_cnt = tot;   // <400 candidates total
    }
    __syncthreads();
    // bucket(key) >= B  <=>  key >= KEY0 + (B<<13); all stored keys > KEY0.
    const uint32_t Tkey = KEY0 + (sh_bucket << 13);
    const unsigned int cnt = sh_cnt;
    const unsigned int cntS = (cnt < SORTN) ? cnt : SORTN;

    // ---- phase 3: gather with DIRECT rank placement.
    // prov = hsuf[bu] + bcnt[bu]++  puts each composite in its bucket's
    // contiguous slot range; bucket is monotone in key, so slots are already
    // globally ordered up to within-bucket permutation (fixed next phase).
#pragma unroll
    for (int uu = 0; uu < KQT; uu++) {
        uint32_t kk[4] = { kq[uu].x, kq[uu].y, kq[uu].z, kq[uu].w };
#pragma unroll
        for (int j = 0; j < 4; j++) {
            uint32_t key = kk[j];
            if (key >= Tkey) {
                unsigned int bu = (key - KEY0) >> 13;
                if (bu > NBUCK - 1u) bu = NBUCK - 1u;
                unsigned int prov = hsuf[bu] + atomicAdd(&bcnt[bu], 1u);
                if (prov < SORTN) {
                    unsigned int idx = ((unsigned int)(tid + (uu << 10)) << 2) + (unsigned int)j;
                    u.s.cbuf[prov] = ((unsigned long long)key << 32) |
                                     (unsigned long long)(0xFFFFFFFFu - idx);
                }
            }
        }
    }
    __syncthreads();

    // ---- phase 4: within-bucket fix-up (exact composite order; groups are
    // ~1-3 slots at the boundary). Reads before barrier, writes after.
    {
        unsigned long long ct = 0ull; unsigned int rk = 0; bool act = false;
        if ((unsigned int)tid < cntS) {
            ct = u.s.cbuf[tid];
            uint32_t key = (uint32_t)(ct >> 32);
            unsigned int bu = (key - KEY0) >> 13;
            if (bu > NBUCK - 1u) bu = NBUCK - 1u;
            unsigned int gs = hsuf[bu], gc = bcnt[bu];
            rk = (unsigned int)tid;
            if (gc > 1u) {
                unsigned int ge = gs + gc; if (ge > SORTN) ge = SORTN;
                rk = gs;
                for (unsigned int k = gs; k < ge; k++)
                    rk += (u.s.cbuf[k] > ct) ? 1u : 0u;
                act = (rk != (unsigned int)tid);
            }
        }
        __syncthreads();
        if (act && rk < SORTN) u.s.cbuf[rk] = ct;
    }
    __syncthreads();

    // ---- phase 5: decode candidates from ordered cbuf (reference float op
    // order; no fma). Also zero supm, zero candidate pad, computed keepw.
    for (int i2 = tid; i2 < TOPK * 7 + 8; i2 += NT) u.s.supm[i2] = 0ull;
    if (tid >= TOPK && tid < PADK) {          // zero pad: never suppresses
        u.s.cbox[tid] = make_float4(0.f, 0.f, 0.f, 0.f);
        u.s.car[tid] = 0.f;
    }
    if (tid < 8) {
        int cntc = (cnt < TOPK) ? (int)cnt : TOPK;
        int rem = cntc - (tid << 6);
        keepw[tid] = (rem <= 0) ? 0ull : ((rem >= 64) ? ~0ull : ((1ull << rem) - 1ull));
    }
    if (tid < TOPK) {
        const int t = tid;
        unsigned long long c = u.s.cbuf[t];
        uint32_t key = (uint32_t)(c >> 32);
        uint32_t idx = 0xFFFFFFFFu - (uint32_t)(c & 0xFFFFFFFFull);
        int valid = (key != 0u) && (idx < NN);
        float x1 = 0.f, y1 = 0.f, x2 = 0.f, y2 = 0.f;
        int lab = 0;
        if (valid) {
            const float* p = img + (size_t)idx * CI;
            float l0 = p[0], l1 = p[1], l2 = p[2], l3 = p[3], c0 = p[4], c1 = p[5];
            const float* pr = priors + (size_t)idx * 4;
            float px = pr[0], py = pr[1], pw = pr[2], ph = pr[3];
            float cxv = __fadd_rn(px, __fmul_rn(__fmul_rn(l0, 0.1f), pw));
            float cyv = __fadd_rn(py, __fmul_rn(__fmul_rn(l1, 0.1f), ph));
            float ew = __fmul_rn(pw, expf(__fmul_rn(l2, 0.2f)));
            float eh = __fmul_rn(ph, expf(__fmul_rn(l3, 0.2f)));
            float hw = __fmul_rn(ew, 0.5f);
            float hh = __fmul_rn(eh, 0.5f);
            x1 = __fsub_rn(cxv, hw); y1 = __fsub_rn(cyv, hh);
            x2 = __fadd_rn(cxv, hw); y2 = __fadd_rn(cyv, hh);
            lab = (c1 > c0) ? 1 : 0;
        }
        u.s.cbox[t] = make_float4(x1, y1, x2, y2);
        u.s.csc[t] = __uint_as_float(key);
        u.s.car[t] = __fmul_rn(__fsub_rn(x2, x1), __fsub_rn(y2, y1));
        u.s.clab[t] = lab;
    }
    __syncthreads();

    // ---- phase 6: suppression bit-matrix via per-wave ballot.
    {
        float4 bjv[7]; float ajv[7];
#pragma unroll
        for (int jw = 0; jw < 7; jw++) {
            int j = (jw << 6) + lane;
            bjv[jw] = u.s.cbox[j];
            ajv[jw] = u.s.car[j];
        }
        float4 bi = u.s.cbox[wid];
        float ai = u.s.car[wid];
        for (int i = wid; i < TOPK; i += 16) {
            float4 bi_n = u.s.cbox[i + 16];   // prefetch next row (pad-safe)
            float ai_n = u.s.car[i + 16];
            const int jw0 = i >> 6;           // wave-uniform
            unsigned long long dmask = (~0ull << (i & 63)) << 1;
#pragma unroll
            for (int jw = 0; jw < 7; jw++) {
                if (jw < jw0) continue;
                float4 bj = bjv[jw]; float aj = ajv[jw];
                float iw = fmaxf(__fsub_rn(fminf(bi.z, bj.z), fmaxf(bi.x, bj.x)), 0.0f);
                float ih = fmaxf(__fsub_rn(fminf(bi.w, bj.w), fmaxf(bi.y, bj.y)), 0.0f);
                float inter = __fmul_rn(iw, ih);
                float denom = __fadd_rn(__fsub_rn(__fadd_rn(ai, aj), inter), 1e-12f);
                bool bit = (double)inter > (double)denom * IOU_C;
                unsigned long long word = __ballot(bit);
                if (lane == 0) {
                    if (jw == jw0) word &= dmask;
                    u.s.supm[i * 7 + jw] = word;
                }
            }
            bi = bi_n; ai = ai_n;
        }
    }
    __syncthreads();

    // ---- phase 7: sequential resolve; readlane (compile-time-uniform index
    // after full unroll) keeps the 400-step dependent chain on the VALU.
    if (tid < 64) {
        int w = tid & 7;                     // lanes 0-6 own words; rest shadow
        unsigned long long kw = keepw[w];
        unsigned long long rr[16], nn[16];   // compile-time-indexed after unroll
#pragma unroll
        for (int k = 0; k < 16; k++) rr[k] = u.s.supm[k * 7 + w];
        for (int base = 0; base < TOPK; base += 16) {
            int nb = base + 16;
            int gb = (nb < TOPK) ? nb : base;
#pragma unroll
            for (int k = 0; k < 16; k++) nn[k] = u.s.supm[(gb + k) * 7 + w];
#pragma unroll
            for (int k = 0; k < 16; k++) {
                int i = base + k;
                unsigned int lo = (unsigned int)__builtin_amdgcn_readlane((int)(unsigned int)kw, i >> 6);
                unsigned int hi = (unsigned int)__builtin_amdgcn_readlane((int)(unsigned int)(kw >> 32), i >> 6);
                unsigned int sel = ((i & 63) < 32) ? lo : hi;
                if ((sel >> (i & 31)) & 1u) kw &= ~rr[k];
            }
#pragma unroll
            for (int k = 0; k < 16; k++) rr[k] = nn[k];
        }
        if (tid < 7) keepw[tid] = kw;
    }
    __syncthreads();

    // ---- phase 8: rank via suffix-popcount over kept (csc is sorted desc),
    // exact tie correction by local walk (ties are O(0) for float scores).
    if (tid < TOPK) {
        const int t = tid;
        if ((keepw[t >> 6] >> (t & 63)) & 1ull) {
            float st = u.s.csc[t];
            int rank = 0;
#pragma unroll
            for (int w = 0; w < 7; w++) {
                unsigned long long kws = keepw[w];
                int jb = w << 6;
                unsigned long long m;
                if (t >= jb + 63)      m = 0ull;           // no bits > t here
                else if (t < jb)       m = ~0ull;          // whole word > t
                else                   m = ~((1ull << (t - jb + 1)) - 1ull);
                rank += __popcll(kws & m);
            }
            for (int j = t + 1; j < TOPK && u.s.csc[j] == st; j++)
                if ((keepw[j >> 6] >> (j & 63)) & 1ull) rank--;
            for (int j = t - 1; j >= 0 && u.s.csc[j] == st; j--)
                if ((keepw[j >> 6] >> (j & 63)) & 1ull) rank++;
            if (rank < KEEPK) {
                float4 bx = u.s.cbox[t];
                float* row = oimg + (size_t)rank * 6;
                row[0] = (float)u.s.clab[t];
                row[1] = st;
                row[2] = bx.x; row[3] = bx.y; row[4] = bx.z; row[5] = bx.w;
            }
        }
    }
}

extern "C" void kernel_launch(void* const* d_in, const int* in_sizes, int n_in,
                              void* d_out, int out_size, void* d_ws, size_t ws_size,
                              hipStream_t stream) {
    const float* pred = (const float*)d_in[0];     // (128, 32768, 6)
    const float* priors = (const float*)d_in[1];   // (32768, 4)
    float* out = (float*)d_out;                    // (128, 200, 6)
    uint32_t* keys = (uint32_t*)d_ws;              // 16 MB scratch
    score_kernel<<<(BB * NN) / STILE, 256, 0, stream>>>(pred, keys);
    boxsel2_kernel<<<BB, NT, 0, stream>>>(pred, priors, keys, out);
}